// Round 8
// baseline (828.340 us; speedup 1.0000x reference)
//
#include <hip/hip_runtime.h>

// PositiveWaveFunction: 32-step tanh RNN, batch 8192, hidden 1024.
// R8: R7 (3-buffer counted-vmcnt pipeline, 128x256 tile, 8 waves, swizzled
// global_load_lds) + m201-style phase discipline: each half-K-tile is
// {ds_read frags || issue stage -> s_barrier -> lgkmcnt(0) -> setprio(1)
//  16xMFMA setprio(0) -> s_barrier}; per-tile boundary keeps the counted
// s_waitcnt vmcnt(6) (never a mid-loop full drain). This creates the wave
// role-split that makes setprio/phase-overlap pay (T3+T4 -> T5 gate).

typedef __bf16 bf16;
typedef __bf16 bf16x8 __attribute__((ext_vector_type(8)));
typedef float  f32x4  __attribute__((ext_vector_type(4)));

#define HID   1024
#define BATCH 8192
#define NSPIN 32

#define AS1 __attribute__((address_space(1)))
#define AS3 __attribute__((address_space(3)))

__device__ __forceinline__ float tanh_fast(float x) {
    float ax = fabsf(x);
    float t  = __expf(-2.0f * ax);                       // (0,1], no overflow
    float r  = (1.0f - t) * __builtin_amdgcn_rcpf(1.0f + t);
    return __builtin_copysignf(r, x);
}

// ---------------- prep kernels ----------------

__global__ void prep1(const float* __restrict__ din, const float* __restrict__ Wih,
                      const float* __restrict__ Whh, const float* __restrict__ bih,
                      const float* __restrict__ bhh,
                      bf16* __restrict__ Wbf, float* __restrict__ u0, float* __restrict__ u1,
                      unsigned int* __restrict__ words, float* __restrict__ fact) {
    long idx = (long)blockIdx.x * blockDim.x + threadIdx.x;
    long stride = (long)gridDim.x * blockDim.x;
    for (long i = idx; i < (long)HID * HID; i += stride) Wbf[i] = (bf16)Whh[i];
    for (long i = idx; i < HID; i += stride) {
        u0[i] = Wih[i * 2 + 0] + bih[i] + bhh[i];
        u1[i] = Wih[i * 2 + 1] + bih[i] + bhh[i];
    }
    for (long b = idx; b < BATCH; b += stride) {
        unsigned int wv = 0;
        for (int j = 0; j < 31; ++j)
            wv |= (din[((long)j * BATCH + b) * 2 + 1] != 0.0f ? 1u : 0u) << j;
        words[b] = wv;
    }
    if (idx == 0) {  // factorials: float64 cumprod cast to float32, like reference
        double f = 1.0; fact[0] = 1.0f;
        for (int k = 1; k <= NSPIN; ++k) { f *= k; fact[k] = (float)f; }
    }
}

// single block: h after step 0 (identical for all batch rows) + its logits
__global__ void prep2(const float* __restrict__ u0, const float* __restrict__ Wlin,
                      const float* __restrict__ blin,
                      bf16* __restrict__ hrow, float* __restrict__ l0s) {
    __shared__ float red0[16], red1[16];
    int t = threadIdx.x;  // 0..1023
    float hv = tanh_fast(u0[t]);
    hrow[t] = (bf16)hv;
    float s0 = hv * Wlin[t], s1 = hv * Wlin[HID + t];
    #pragma unroll
    for (int off = 1; off < 64; off <<= 1) {
        s0 += __shfl_xor(s0, off, 64);
        s1 += __shfl_xor(s1, off, 64);
    }
    if ((t & 63) == 0) { red0[t >> 6] = s0; red1[t >> 6] = s1; }
    __syncthreads();
    if (t == 0) {
        float a = blin[0], b = blin[1];
        for (int i = 0; i < 16; ++i) { a += red0[i]; b += red1[i]; }
        l0s[0] = a; l0s[1] = b;
    }
}

// broadcast hrow to all 8192 rows of the ping buffer
__global__ void fillh(const bf16* __restrict__ hrow, bf16* __restrict__ hping) {
    const bf16x8* src = (const bf16x8*)hrow;   // 128 vectors per row
    bf16x8* dst = (bf16x8*)hping;
    long n8 = (long)BATCH * HID / 8;
    for (long v = (long)blockIdx.x * blockDim.x + threadIdx.x; v < n8;
         v += (long)gridDim.x * blockDim.x)
        dst[v] = src[v & 127];
}

// ---------------- main recurrence GEMM ----------------
// Z = h_in @ W_hh^T ; z += (bit ? u1 : u0) ; h_out = tanh(z) (bf16)
// partial logits per wave-column -> plog[31][8192][16][2]
// Tile 128x256, BK=64, 8 waves (2x4 of 64x64), 16x16x32 bf16 MFMA.
// 3-buffer LDS pipeline, counted vmcnt(6) at tile boundaries, per-phase
// barrier + lgkmcnt(0) + setprio MFMA clusters.

__global__ __launch_bounds__(512, 2) void gemm_step(
        const bf16* __restrict__ hin, bf16* __restrict__ hout,
        const bf16* __restrict__ Wbf,
        const float* __restrict__ u0, const float* __restrict__ u1,
        const unsigned int* __restrict__ words, int sbit,
        const float* __restrict__ Wlin,
        float* __restrict__ plog_s) {
    __shared__ __align__(16) bf16 sA0[128 * 64];
    __shared__ __align__(16) bf16 sA1[128 * 64];
    __shared__ __align__(16) bf16 sA2[128 * 64];
    __shared__ __align__(16) bf16 sB0[256 * 64];
    __shared__ __align__(16) bf16 sB1[256 * 64];
    __shared__ __align__(16) bf16 sB2[256 * 64];

    const int tid = threadIdx.x;
    const int w = tid >> 6, l = tid & 63;
    const long rowM = (long)blockIdx.x * 128;
    const int  colN = blockIdx.y * 256;

    const int wr = w >> 2, wc = w & 3;      // 2x4 wave grid (64x64 tiles)
    const int fr = l & 15, fq = l >> 4;     // fragment lane coords

    f32x4 acc[4][4] = {};

    // staging row/chunk decomposition (per lane): 8 rows x 8 chunks per issue
    const int lrow = l >> 3;                 // 0..7
    const int lchk = l & 7;                  // 0..7 (16B chunk)

// stage A-half-tile rows (2 loads) / B rows pair (2 loads), 16B chunks,
// source pre-permuted so linear LDS dest == XOR-swizzled layout
#define STG_A(SA, KT) do {                                                                   \
    _Pragma("unroll")                                                                        \
    for (int i = 0; i < 2; ++i) {                                                            \
        const int r_ = w * 16 + i * 8 + lrow;                                                \
        const int sc_ = (lchk ^ (r_ & 7)) * 8;                                               \
        __builtin_amdgcn_global_load_lds(                                                    \
            (const AS1 void*)(hin + (rowM + r_) * HID + (KT) * 64 + sc_),                    \
            (AS3 void*)(&SA[(w * 16 + i * 8) * 64]), 16, 0, 0);                              \
    }                                                                                        \
} while (0)

#define STG_B2(SB, KT, I0) do {                                                              \
    _Pragma("unroll")                                                                        \
    for (int i = (I0); i < (I0) + 2; ++i) {                                                  \
        const int r_ = w * 32 + i * 8 + lrow;                                                \
        const int sc_ = (lchk ^ (r_ & 7)) * 8;                                               \
        __builtin_amdgcn_global_load_lds(                                                    \
            (const AS1 void*)(Wbf + (long)(colN + r_) * HID + (KT) * 64 + sc_),              \
            (AS3 void*)(&SB[(w * 32 + i * 8) * 64]), 16, 0, 0);                              \
    }                                                                                        \
} while (0)

#define RD_FRAGS(AF, BF, SA, SB, KK) do {                                                    \
    _Pragma("unroll")                                                                        \
    for (int m = 0; m < 4; ++m) {                                                            \
        const int ra_ = wr * 64 + m * 16 + fr;                                               \
        AF[m] = *(const bf16x8*)&SA[ra_ * 64 + (((KK) * 32 + fq * 8) ^ ((ra_ & 7) << 3))];   \
    }                                                                                        \
    _Pragma("unroll")                                                                        \
    for (int n = 0; n < 4; ++n) {                                                            \
        const int rb_ = wc * 64 + n * 16 + fr;                                               \
        BF[n] = *(const bf16x8*)&SB[rb_ * 64 + (((KK) * 32 + fq * 8) ^ ((rb_ & 7) << 3))];   \
    }                                                                                        \
} while (0)

#define MFMA16(AF, BF) do {                                                                  \
    __builtin_amdgcn_s_setprio(1);                                                           \
    _Pragma("unroll")                                                                        \
    for (int m = 0; m < 4; ++m)                                                              \
        _Pragma("unroll")                                                                    \
        for (int n = 0; n < 4; ++n)                                                          \
            acc[m][n] = __builtin_amdgcn_mfma_f32_16x16x32_bf16(AF[m], BF[n], acc[m][n], 0, 0, 0); \
    __builtin_amdgcn_s_setprio(0);                                                           \
} while (0)

// one K-tile = 2 phases; each phase: {ds_read frags || stage-issue ->
// barrier -> lgkmcnt(0) -> MFMA cluster -> barrier}. Boundary: counted vmcnt
// (tile T+1 landed; T+2 still in flight) + raw barrier.
#define BODY(CA, CB, NA, NB, T) do {                                                         \
    bf16x8 afx[4], bfx[4], afy[4], bfy[4];                                                   \
    RD_FRAGS(afx, bfx, CA, CB, 0);                                                           \
    if ((T) <= 13) { STG_A(NA, (T) + 2); STG_B2(NB, (T) + 2, 0); }                           \
    __builtin_amdgcn_s_barrier();                                                            \
    asm volatile("s_waitcnt lgkmcnt(0)" ::: "memory");                                       \
    __builtin_amdgcn_sched_barrier(0);                                                       \
    MFMA16(afx, bfx);                                                                        \
    __builtin_amdgcn_s_barrier();                                                            \
    RD_FRAGS(afy, bfy, CA, CB, 1);                                                           \
    if ((T) <= 13) { STG_B2(NB, (T) + 2, 2); }                                               \
    __builtin_amdgcn_s_barrier();                                                            \
    asm volatile("s_waitcnt lgkmcnt(0)" ::: "memory");                                       \
    __builtin_amdgcn_sched_barrier(0);                                                       \
    MFMA16(afy, bfy);                                                                        \
    __builtin_amdgcn_sched_barrier(0);                                                       \
    if ((T) <= 13)       asm volatile("s_waitcnt vmcnt(6)" ::: "memory");                    \
    else if ((T) == 14)  asm volatile("s_waitcnt vmcnt(0)" ::: "memory");                    \
    if ((T) <= 14) __builtin_amdgcn_s_barrier();                                             \
    __builtin_amdgcn_sched_barrier(0);                                                       \
} while (0)

    // prologue: tiles 0 and 1 in flight; wait tile 0 (6 newest = tile 1 fly on)
    STG_A(sA0, 0); STG_B2(sB0, 0, 0); STG_B2(sB0, 0, 2);
    STG_A(sA1, 1); STG_B2(sB1, 1, 0); STG_B2(sB1, 1, 2);
    __builtin_amdgcn_sched_barrier(0);
    asm volatile("s_waitcnt vmcnt(6)" ::: "memory");
    __builtin_amdgcn_s_barrier();
    __builtin_amdgcn_sched_barrier(0);

    BODY(sA0, sB0, sA2, sB2, 0);
    BODY(sA1, sB1, sA0, sB0, 1);
    BODY(sA2, sB2, sA1, sB1, 2);
    BODY(sA0, sB0, sA2, sB2, 3);
    BODY(sA1, sB1, sA0, sB0, 4);
    BODY(sA2, sB2, sA1, sB1, 5);
    BODY(sA0, sB0, sA2, sB2, 6);
    BODY(sA1, sB1, sA0, sB0, 7);
    BODY(sA2, sB2, sA1, sB1, 8);
    BODY(sA0, sB0, sA2, sB2, 9);
    BODY(sA1, sB1, sA0, sB0, 10);
    BODY(sA2, sB2, sA1, sB1, 11);
    BODY(sA0, sB0, sA2, sB2, 12);
    BODY(sA1, sB1, sA0, sB0, 13);
    BODY(sA2, sB2, sA1, sB1, 14);
    BODY(sA0, sB0, sA2, sB2, 15);

#undef BODY
#undef MFMA16
#undef RD_FRAGS
#undef STG_A
#undef STG_B2

    // epilogue: bias-select + tanh + bf16 store + partial logits
    // (all VMEM here is AFTER the loop; in-loop vmcnt counting stays exact)
    float u0v[4], u1v[4], wl0[4], wl1[4];
    int colg[4];
    #pragma unroll
    for (int n = 0; n < 4; ++n) {
        int c = colN + wc * 64 + n * 16 + fr;
        colg[n] = c;
        u0v[n] = u0[c]; u1v[n] = u1[c];
        wl0[n] = Wlin[c]; wl1[n] = Wlin[HID + c];
    }
    const int slot = blockIdx.y * 4 + wc;   // 16 slots

    #pragma unroll
    for (int m = 0; m < 4; ++m) {
        #pragma unroll
        for (int r = 0; r < 4; ++r) {
            long rowg = rowM + wr * 64 + m * 16 + fq * 4 + r;
            int bt = (words[rowg] >> sbit) & 1;
            float s0 = 0.f, s1 = 0.f;
            #pragma unroll
            for (int n = 0; n < 4; ++n) {
                float z  = acc[m][n][r] + (bt ? u1v[n] : u0v[n]);
                float hv = tanh_fast(z);
                hout[rowg * HID + colg[n]] = (bf16)hv;
                s0 += hv * wl0[n];
                s1 += hv * wl1[n];
            }
            #pragma unroll
            for (int off = 1; off < 16; off <<= 1) {
                s0 += __shfl_xor(s0, off, 16);
                s1 += __shfl_xor(s1, off, 16);
            }
            if (fr == 0)
                *(float2*)&plog_s[rowg * 32 + slot * 2] = make_float2(s0, s1);
        }
    }
}

// ---------------- finalize: softmax + permutation weights ----------------

__global__ void finalize(const float* __restrict__ plog, const float* __restrict__ l0s,
                         const float* __restrict__ blin, const unsigned int* __restrict__ words,
                         const float* __restrict__ fact, float* __restrict__ out) {
    long idx = (long)blockIdx.x * blockDim.x + threadIdx.x;
    if (idx >= (long)NSPIN * BATCH) return;
    int s = (int)(idx / BATCH), b = (int)(idx % BATCH);

    float l0, l1;
    if (s == 0) { l0 = l0s[0]; l1 = l0s[1]; }
    else {
        l0 = blin[0]; l1 = blin[1];
        const float* ps = plog + ((long)(s - 1) * BATCH + b) * 32;
        #pragma unroll
        for (int k = 0; k < 16; ++k) {
            l0 += ps[k * 2 + 0];
            l1 += ps[k * 2 + 1];
        }
    }
    float mx = fmaxf(l0, l1);
    float e0 = __expf(l0 - mx), e1 = __expf(l1 - mx);
    float p0 = e0 / (e0 + e1), p1 = e1 / (e0 + e1);
    if (s > 0) {
        const unsigned int wv = words[b];
        const int cd = __popc(wv & ((1u << s) - 1));
        const float cdf = (float)cd, cuf = (float)(s - cd);
        const float ku = 16.f - cuf, kd = 16.f - cdf;
        const int n = NSPIN - s;
        const int kui = (int)fminf(fmaxf(ku, 0.f), 32.f);
        const int kdi = (int)fminf(fmaxf(kd, 0.f), 32.f);
        const float wu = fact[n] / fact[kui] * (ku >= 0.f ? 1.f : 0.f) + 1e-12f;
        const float wd = fact[n] / fact[kdi] * (kd >= 0.f ? 1.f : 0.f) + 1e-12f;
        p0 *= wu; p1 *= wd;
    }
    float inv = 1.f / (p0 + p1);
    out[idx * 2 + 0] = p0 * inv;
    out[idx * 2 + 1] = p1 * inv;
}

// ---------------- launch ----------------

extern "C" void kernel_launch(void* const* d_in, const int* in_sizes, int n_in,
                              void* d_out, int out_size, void* d_ws, size_t ws_size,
                              hipStream_t stream) {
    const float* din  = (const float*)d_in[0];  // [32][8192][2]
    const float* Wih  = (const float*)d_in[1];  // [1024][2]
    const float* Whh  = (const float*)d_in[2];  // [1024][1024]
    const float* bih  = (const float*)d_in[3];  // [1024]
    const float* bhh  = (const float*)d_in[4];  // [1024]
    const float* Wlin = (const float*)d_in[5];  // [2][1024]
    const float* blin = (const float*)d_in[6];  // [2]
    float* out = (float*)d_out;

    char* ws = (char*)d_ws;
    size_t o = 0;
    auto alloc = [&](size_t b) { size_t r = o; o += (b + 255) & ~(size_t)255; return r; };
    bf16*  Wbf  = (bf16*)(ws + alloc((size_t)HID * HID * 2));
    float* u0   = (float*)(ws + alloc(HID * 4));
    float* u1   = (float*)(ws + alloc(HID * 4));
    bf16*  hrow = (bf16*)(ws + alloc(HID * 2));
    float* l0s  = (float*)(ws + alloc(2 * 4));
    float* fact = (float*)(ws + alloc(33 * 4));
    unsigned int* words = (unsigned int*)(ws + alloc((size_t)BATCH * 4));
    bf16*  hA   = (bf16*)(ws + alloc((size_t)BATCH * HID * 2));
    bf16*  hB   = (bf16*)(ws + alloc((size_t)BATCH * HID * 2));
    float* plog = (float*)(ws + alloc(31L * BATCH * 16 * 2 * 4));

    prep1<<<1024, 256, 0, stream>>>(din, Wih, Whh, bih, bhh, Wbf, u0, u1, words, fact);
    prep2<<<1, 1024, 0, stream>>>(u0, Wlin, blin, hrow, l0s);
    fillh<<<2048, 256, 0, stream>>>(hrow, hA);

    bf16* hin = hA; bf16* hout = hB;
    for (int s = 1; s <= 31; ++s) {
        gemm_step<<<dim3(64, 4), 512, 0, stream>>>(
            hin, hout, Wbf, u0, u1, words, s - 1, Wlin,
            plog + (size_t)(s - 1) * BATCH * 32);
        bf16* t = hin; hin = hout; hout = t;
    }
    finalize<<<(NSPIN * BATCH) / 256, 256, 0, stream>>>(plog, l0s, blin, words, fact, out);
}